// Round 1
// baseline (96.640 us; speedup 1.0000x reference)
//
#include <hip/hip_runtime.h>

#define TIMESTEPS 1000
#define BATCH 64
#define HDIM 256
#define WDIM 256
#define NROWS (BATCH * HDIM)              // 16384 (b,h) rows
// total elements averaged over: 64 * 1 * 256 * 1000
#define TOTAL_ELEMS 16384000.0

// One block per (b,h) row. 256 threads, thread i owns column w = i.
__global__ __launch_bounds__(256) void holo_row_loss(
    const float* __restrict__ rec,
    const float* __restrict__ tgt,
    float* __restrict__ partials)
{
    __shared__ int binsR[TIMESTEPS];
    __shared__ int binsT[TIMESTEPS];
    __shared__ float wave_sums[4];

    const int tid = threadIdx.x;
    const int row = blockIdx.x;           // 0 .. NROWS-1

    // zero the bins (empty bin == 0 matches reference's zeros + max(w>=0))
    for (int t = tid; t < TIMESTEPS; t += 256) {
        binsR[t] = 0;
        binsT[t] = 0;
    }
    __syncthreads();

    // coalesced row loads: rows are contiguous 256-float runs
    const float xr = rec[row * WDIM + tid];
    const float xt = tgt[row * WDIM + tid];

    // q = (int(x*1000) - 1) mod 1000, drop x == 0.
    // f32 mul + trunc matches jnp astype(int32) bit-for-bit; q in [-1, 998].
    if (xr != 0.0f) {
        int q = (int)(xr * 1000.0f) - 1;
        if (q < 0) q += TIMESTEPS;
        atomicMax(&binsR[q], tid);
    }
    if (xt != 0.0f) {
        int q = (int)(xt * 1000.0f) - 1;
        if (q < 0) q += TIMESTEPS;
        atomicMax(&binsT[q], tid);
    }
    __syncthreads();

    // per-thread partial over ~4 bins each
    float s = 0.0f;
    for (int t = tid; t < TIMESTEPS; t += 256) {
        float d = (float)(binsR[t] - binsT[t]);
        s += d * d;
    }

    // wave (64-lane) shuffle reduce, then cross-wave via LDS
    for (int off = 32; off > 0; off >>= 1) s += __shfl_down(s, off, 64);
    if ((tid & 63) == 0) wave_sums[tid >> 6] = s;
    __syncthreads();
    if (tid == 0)
        partials[row] = wave_sums[0] + wave_sums[1] + wave_sums[2] + wave_sums[3];
}

// Single-block deterministic final reduction in double.
__global__ __launch_bounds__(256) void reduce_partials(
    const float* __restrict__ partials,
    float* __restrict__ out)
{
    __shared__ double wave_sums[4];
    const int tid = threadIdx.x;
    double s = 0.0;
    for (int i = tid; i < NROWS; i += 256) s += (double)partials[i];
    for (int off = 32; off > 0; off >>= 1) s += __shfl_down(s, off, 64);
    if ((tid & 63) == 0) wave_sums[tid >> 6] = s;
    __syncthreads();
    if (tid == 0) {
        double tot = wave_sums[0] + wave_sums[1] + wave_sums[2] + wave_sums[3];
        out[0] = (float)(tot / TOTAL_ELEMS);
    }
}

extern "C" void kernel_launch(void* const* d_in, const int* in_sizes, int n_in,
                              void* d_out, int out_size, void* d_ws, size_t ws_size,
                              hipStream_t stream)
{
    const float* rec = (const float*)d_in[0];
    const float* tgt = (const float*)d_in[1];
    float* out = (float*)d_out;
    float* partials = (float*)d_ws;        // needs NROWS * 4 = 64 KiB

    holo_row_loss<<<NROWS, 256, 0, stream>>>(rec, tgt, partials);
    reduce_partials<<<1, 256, 0, stream>>>(partials, out);
}

// Round 2
// 75.759 us; speedup vs baseline: 1.2756x; 1.2756x over previous
//
#include <hip/hip_runtime.h>

#define TIMESTEPS 1000
#define NROWS 16384                 // 64 batch * 256 H rows
#define ROWS_PER_WAVE 4
#define WAVES_PER_BLOCK 4
#define NBLOCKS (NROWS / (ROWS_PER_WAVE * WAVES_PER_BLOCK))   // 1024
#define NPARTIALS (NROWS / ROWS_PER_WAVE)                     // 4096
#define TOTAL_ELEMS 16384000.0      // 64 * 1 * 256 * 1000

// Wave-synchronous: each 64-lane wave owns a private 2048-int LDS region
// (R bins at [0..999], T bins at [1024..2023], rest is zero padding) and
// processes ROWS_PER_WAVE rows with NO __syncthreads. DS ops from a single
// wave complete in order; wave_barrier() pins compiler instruction order.
__global__ __launch_bounds__(256) void holo_row_loss(
    const float* __restrict__ rec,
    const float* __restrict__ tgt,
    float* __restrict__ partials)
{
    __shared__ int bins[WAVES_PER_BLOCK][2048];   // 32 KiB

    const int tid  = threadIdx.x;
    const int wav  = tid >> 6;
    const int lane = tid & 63;
    const int gw   = blockIdx.x * WAVES_PER_BLOCK + wav;   // global wave id

    int* __restrict__ binw = &bins[wav][0];

    // zero this wave's 2048 ints: 8 x int4 per lane, stride-16B fast layout
    int4 z4; z4.x = 0; z4.y = 0; z4.z = 0; z4.w = 0;
    int4* zb = (int4*)binw;
#pragma unroll
    for (int j = 0; j < 8; ++j) zb[j * 64 + lane] = z4;
    __builtin_amdgcn_wave_barrier();

    const float4* rec4 = (const float4*)rec;
    const float4* tgt4 = (const float4*)tgt;

    float s = 0.0f;   // exact: integer-valued partial stays < 2^24 per lane

#pragma unroll 1
    for (int r = 0; r < ROWS_PER_WAVE; ++r) {
        const int row = gw * ROWS_PER_WAVE + r;
        // one row = 256 floats = 64 float4; lane owns cols lane*4..lane*4+3
        const float4 xr = rec4[row * 64 + lane];
        const float4 xt = tgt4[row * 64 + lane];

        int qr[4], qt[4];
#pragma unroll
        for (int j = 0; j < 4; ++j) {
            const float vr = (&xr.x)[j];
            const float vt = (&xt.x)[j];
            const int   w  = lane * 4 + j;
            // q = (int(x*1000) - 1) mod 1000, x==0 dropped. f32 mul + trunc
            // matches jnp astype(int32); q in [-1, 998] for x in [0,1).
            int q = (int)(vr * 1000.0f) - 1;
            if (q < 0) q += TIMESTEPS;
            if (vr != 0.0f) { atomicMax(&binw[q], w); qr[j] = q; }
            else            { qr[j] = 1012; }          // pad slot, stays 0
            q = (int)(vt * 1000.0f) - 1;
            if (q < 0) q += TIMESTEPS;
            if (vt != 0.0f) { atomicMax(&binw[1024 + q], w); qt[j] = q; }
            else            { qt[j] = 1012; }
        }
        __builtin_amdgcn_wave_barrier();

        // sum phase: lane reads 4+4 int4 (stride-16B), diff^2 accumulate.
        // pad bins [1000..1023] are 0 in both halves -> contribute 0.
        const int4* r4 = (const int4*)binw;
        const int4* t4 = (const int4*)(binw + 1024);
#pragma unroll
        for (int k = 0; k < 4; ++k) {
            const int4 a = r4[k * 64 + lane];
            const int4 b = t4[k * 64 + lane];
            const float d0 = (float)(a.x - b.x);
            const float d1 = (float)(a.y - b.y);
            const float d2 = (float)(a.z - b.z);
            const float d3 = (float)(a.w - b.w);
            s = fmaf(d0, d0, s);
            s = fmaf(d1, d1, s);
            s = fmaf(d2, d2, s);
            s = fmaf(d3, d3, s);
        }
        __builtin_amdgcn_wave_barrier();

        // re-zero ONLY the bins this lane scattered to (dup writes of 0 ok)
#pragma unroll
        for (int j = 0; j < 4; ++j) {
            binw[qr[j]] = 0;
            binw[1024 + qt[j]] = 0;
        }
        __builtin_amdgcn_wave_barrier();
    }

    // one shuffle reduce per wave
    for (int off = 32; off > 0; off >>= 1) s += __shfl_down(s, off, 64);
    if (lane == 0) partials[gw] = s;
}

// Deterministic final reduction: 256 threads, 16 independent loads each.
__global__ __launch_bounds__(256) void reduce_partials(
    const float* __restrict__ partials,
    float* __restrict__ out)
{
    __shared__ double wave_sums[4];
    const int tid = threadIdx.x;
    double s = 0.0;
#pragma unroll
    for (int i = 0; i < NPARTIALS / 256; ++i)
        s += (double)partials[i * 256 + tid];
    for (int off = 32; off > 0; off >>= 1) s += __shfl_down(s, off, 64);
    if ((tid & 63) == 0) wave_sums[tid >> 6] = s;
    __syncthreads();
    if (tid == 0) {
        double tot = wave_sums[0] + wave_sums[1] + wave_sums[2] + wave_sums[3];
        out[0] = (float)(tot / TOTAL_ELEMS);
    }
}

extern "C" void kernel_launch(void* const* d_in, const int* in_sizes, int n_in,
                              void* d_out, int out_size, void* d_ws, size_t ws_size,
                              hipStream_t stream)
{
    const float* rec = (const float*)d_in[0];
    const float* tgt = (const float*)d_in[1];
    float* out = (float*)d_out;
    float* partials = (float*)d_ws;        // NPARTIALS * 4 = 16 KiB

    holo_row_loss<<<NBLOCKS, 256, 0, stream>>>(rec, tgt, partials);
    reduce_partials<<<1, 256, 0, stream>>>(partials, out);
}